// Round 10
// baseline (105.216 us; speedup 1.0000x reference)
//
#include <hip/hip_runtime.h>

// Problem constants
#define NROWS 8192   // 4 * 2048
#define DIM   512
#define NT    64                    // 8192 / 128 tiles per side
#define NTRI  (NT * (NT + 1) / 2)   // 2080 upper-triangular tile blocks
#define NACC  64                    // accumulator slots (contention spread)

using f32x4 = __attribute__((ext_vector_type(4))) float;

typedef __attribute__((address_space(1))) const void* as1_cvptr;
typedef __attribute__((address_space(3))) void*       as3_vptr;

// async global->LDS DMA, 16B per lane; LDS dest = wave-uniform base + lane*16
__device__ __forceinline__ void async16(const void* g, void* l) {
    __builtin_amdgcn_global_load_lds((as1_cvptr)g, (as3_vptr)l, 16, 0, 0);
}

// Software fp32 -> OCP e4m3fn, round-to-nearest-even (fp8 cvt builtin was the
// r6 crash suspect; this SW encoder is r7-r9-verified, absmax passed).
__device__ __forceinline__ unsigned char f2e4m3(float x) {
    unsigned ux = __float_as_uint(x);
    unsigned s  = (ux >> 24) & 0x80u;
    float a = __uint_as_float(ux & 0x7FFFFFFFu);     // |x|, finite for our data
    a = fminf(a, 448.0f);                            // clamp to max finite
    unsigned ua = __float_as_uint(a);
    int eb = (int)(ua >> 23);                        // biased exponent
    if (eb < 121) eb = 121;                          // denormal region: step 2^-9
    float step  = __uint_as_float((unsigned)(eb - 3) << 23);    // 2^(eb-130)
    float istep = __uint_as_float((unsigned)(257 - eb) << 23);  // 2^(130-eb), exact
    float q = rintf(a * istep) * step;               // RNE on e4m3 grid
    q = fminf(q, 448.0f);
    if (q < 0.001953125f)                            // below min denormal 2^-9 -> 0
        return (unsigned char)s;
    unsigned uq = __float_as_uint(q);
    int eq = (int)(uq >> 23) - 127;
    unsigned byte;
    if (eq < -6) byte = (unsigned)(q * 512.0f);      // denormal: d*2^-9, d in 1..7
    else         byte = (unsigned)((eq + 7) << 3) | ((uq >> 20) & 7u);
    return (unsigned char)(s | byte);
}

// Kernel 1: fp32 row norms + fp32->fp8 conversion into a pre-swizzled global
// layout: within each 64B k-slab of row r, 8B chunk c stored at position
// c ^ ((r>>1)&7). (r9's c^(r&7) left fr/fr+8 bank aliases -> 3072
// conflicts/block; (r>>1)&7 is a bijection over each fr-parity class ->
// 16 distinct bank-pairs per 16-lane phase.) One wave per row; a lane's
// 8 elems = one 8B chunk (chunk = lane&7, slab = lane>>3).
__global__ __launch_bounds__(256) void norm_convert_kernel(
    const float* __restrict__ X, unsigned char* __restrict__ Xq,
    float* __restrict__ norms, float* __restrict__ acc)
{
    const int tid  = threadIdx.x;
    const int lane = tid & 63;
    const int w    = tid >> 6;
    const int row  = blockIdx.x * 4 + w;

    if (blockIdx.x == 0 && tid < NACC) acc[tid] = 0.0f;

    const float* xr = X + (size_t)row * DIM + lane * 8;
    float4 v0 = *(const float4*)xr;
    float4 v1 = *(const float4*)(xr + 4);

    float s = 0.0f;
    s = fmaf(v0.x, v0.x, s); s = fmaf(v0.y, v0.y, s);
    s = fmaf(v0.z, v0.z, s); s = fmaf(v0.w, v0.w, s);
    s = fmaf(v1.x, v1.x, s); s = fmaf(v1.y, v1.y, s);
    s = fmaf(v1.z, v1.z, s); s = fmaf(v1.w, v1.w, s);

    union { unsigned char b[8]; uint2 v; } pk;
    pk.b[0] = f2e4m3(v0.x); pk.b[1] = f2e4m3(v0.y);
    pk.b[2] = f2e4m3(v0.z); pk.b[3] = f2e4m3(v0.w);
    pk.b[4] = f2e4m3(v1.x); pk.b[5] = f2e4m3(v1.y);
    pk.b[6] = f2e4m3(v1.z); pk.b[7] = f2e4m3(v1.w);

    const int slab = lane >> 3;                        // 64B slab index (0..7)
    const int cpos = (lane & 7) ^ ((row >> 1) & 7);    // swizzled 8B position
    *(uint2*)(Xq + (size_t)row * DIM + slab * 64 + cpos * 8) = pk.v;

    #pragma unroll
    for (int off = 32; off > 0; off >>= 1) s += __shfl_down(s, off, 64);
    if (lane == 0) norms[row] = s;
}

// Kernel 2: upper-triangular tiled X·X^T (fp8 e4m3 MFMA) + fused sqrt/exp/sum
// epilogue. 128x128 tile/block, 4 waves, 64x64 quadrant/wave, BK=64
// (8 iters of two 16x16x32 k-steps; r9: halving iterations was the win).
//
// Staging via global_load_lds width=16 DMA (r9 analysis: VALUBusy*dur
// constant across rounds -> fixed issue load; register staging was
// 4 loads + 4 ds_writes + addr per thread-iter, DMA is 4 instrs per
// WAVE-iter and frees 16 prefetch VGPRs). DMA for the NEXT buffer is
// issued before the MFMA stream, so it has the full compute stretch
// (~2.4k cyc) to land before the barrier's vmcnt drain (r1's mistake was
// DMA-for-current right before the barrier: zero overlap, 154us).
// LDS image = linear copy of pre-swizzled global rows; frag read at
// fr*64 + ((q ^ ((fr>>1)&7))*8) -> conflict-free; DMA writes are linear.
// NO device-scope fences (r3: agent fence = per-XCD L2 flush, +40us).
__global__ __launch_bounds__(256, 4) void pair_loss_gemm_kernel(
    const unsigned char* __restrict__ Xq, const float* __restrict__ norms,
    float* __restrict__ acc)
{
    __shared__ __align__(16) char As0[8192];
    __shared__ __align__(16) char As1[8192];
    __shared__ __align__(16) char Bs0[8192];
    __shared__ __align__(16) char Bs1[8192];
    __shared__ float wsum[4];

    // decode linear block id -> upper-triangular (bi, bj), bi <= bj
    int t = blockIdx.x, bi = 0;
    while (t >= (NT - bi)) { t -= (NT - bi); bi++; }
    const int bj = bi + t;

    const int tid  = threadIdx.x;
    const int lane = tid & 63;
    const int w    = tid >> 6;

    const int rowA = bi * 128;
    const int rowB = bj * 128;

    f32x4 accv[4][4];
    const f32x4 zero = {0.0f, 0.0f, 0.0f, 0.0f};
    #pragma unroll
    for (int a = 0; a < 4; a++)
        #pragma unroll
        for (int b = 0; b < 4; b++) accv[a][b] = zero;

    // DMA staging: tile = 128 rows x 64B = 512 chunks of 16B. Wave w covers
    // chunks [w*128, w*128+128) as two 1KB instrs (j=0: lanes at w*128+lane,
    // j=1: +64 chunks = +16 rows = +8192B in global, +1024B in LDS).
    const int i0 = w * 128 + lane;
    const int rr = i0 >> 2;
    const int sl = i0 & 3;
    const unsigned char* gAl = Xq + (size_t)(rowA + rr) * DIM + sl * 16;
    const unsigned char* gBl = Xq + (size_t)(rowB + rr) * DIM + sl * 16;
    const int ldw = w * 2048;            // wave-uniform LDS base within tile

    // MFMA fp8 frag: lane holds A[m=fr][k=q*8..q*8+7] per k-step, q=lane>>4.
    // Chunk s*4+q of row fr sits at swizzled position (s*4+q)^((fr>>1)&7)
    // -> fo = fo0 ^ (s<<5).
    const int fr  = lane & 15;
    const int q   = lane >> 4;
    const int fo0 = fr * 64 + ((q ^ ((fr >> 1) & 7)) * 8);
    const int wr  = (w & 1) * 64;
    const int wc  = (w >> 1) * 64;

    // prologue: DMA slab 0 into buffer 0
    async16(gAl,        As0 + ldw);
    async16(gAl + 8192, As0 + ldw + 1024);
    async16(gBl,        Bs0 + ldw);
    async16(gBl + 8192, Bs0 + ldw + 1024);
    __syncthreads();

    char* curA = As0; char* nxtA = As1;
    char* curB = Bs0; char* nxtB = Bs1;

    #pragma unroll 1
    for (int k = 0; k < 8; k++) {
        // frag reads for both k-steps first (regs: 32 + 64 acc ~ fits 128)
        long afr[2][4], bfr[2][4];
        #pragma unroll
        for (int s = 0; s < 2; s++) {
            const int fo = fo0 ^ (s << 5);
            #pragma unroll
            for (int a = 0; a < 4; a++)
                afr[s][a] = *(const long*)(curA + (wr + a * 16) * 64 + fo);
            #pragma unroll
            for (int b = 0; b < 4; b++)
                bfr[s][b] = *(const long*)(curB + (wc + b * 16) * 64 + fo);
        }

        // issue DMA for next slab into the other buffer; lands during MFMAs
        const bool more = (k < 7);
        if (more) {
            const int k0 = (k + 1) * 64;
            async16(gAl + k0,        nxtA + ldw);
            async16(gAl + k0 + 8192, nxtA + ldw + 1024);
            async16(gBl + k0,        nxtB + ldw);
            async16(gBl + k0 + 8192, nxtB + ldw + 1024);
        }

        #pragma unroll
        for (int s = 0; s < 2; s++)
            #pragma unroll
            for (int a = 0; a < 4; a++)
                #pragma unroll
                for (int b = 0; b < 4; b++)
                    accv[a][b] = __builtin_amdgcn_mfma_f32_16x16x32_fp8_fp8(
                        afr[s][a], bfr[s][b], accv[a][b], 0, 0, 0);

        if (more) {
            __syncthreads();   // drains DMA (vmcnt) + all lgkm, publishes nxt
            char* tA = curA; curA = nxtA; nxtA = tA;
            char* tB = curB; curB = nxtB; nxtB = tB;
        }
    }

    // epilogue: term = exp(-0.1*sqrt(max(ni+nj-2*dot, 0))); diag -> 1
    // C/D layout: col = lane&15, row = (lane>>4)*4 + reg (dtype-independent)
    const float wgt = (bi == bj) ? 1.0f : 2.0f;
    float lsum = 0.0f;
    #pragma unroll
    for (int a = 0; a < 4; a++) {
        const int gi0 = rowA + wr + a * 16 + (lane >> 4) * 4;
        #pragma unroll
        for (int b = 0; b < 4; b++) {
            const int gj = rowB + wc + b * 16 + (lane & 15);
            const float nj = norms[gj];
            #pragma unroll
            for (int r = 0; r < 4; r++) {
                const int gi = gi0 + r;
                float sq = fmaf(-2.0f, accv[a][b][r], norms[gi] + nj);
                sq = fmaxf(sq, 0.0f);
                float term = __expf(-0.1f * sqrtf(sq));
                if (gi == gj) term = 1.0f;
                lsum += term;
            }
        }
    }
    lsum *= wgt;
    #pragma unroll
    for (int off = 32; off > 0; off >>= 1) lsum += __shfl_down(lsum, off, 64);
    if (lane == 0) wsum[w] = lsum;
    __syncthreads();
    if (tid == 0)
        atomicAdd(&acc[blockIdx.x & (NACC - 1)],
                  wsum[0] + wsum[1] + wsum[2] + wsum[3]);
}

// Kernel 3: finalize scalar outputs (sum NACC slots)
__global__ void finalize_kernel(const float* __restrict__ acc,
                                float* __restrict__ out)
{
    const int lane = threadIdx.x;
    float s = (lane < NACC) ? acc[lane] : 0.0f;
    #pragma unroll
    for (int off = 32; off > 0; off >>= 1) s += __shfl_down(s, off, 64);
    if (lane == 0) {
        const float inv = 1.0f / ((float)NROWS * (float)NROWS); // 2^-26 exact
        float loss = s * inv * 0.1f;
        out[0] = loss;
        out[1] = 0.5f * loss;
    }
}

extern "C" void kernel_launch(void* const* d_in, const int* in_sizes, int n_in,
                              void* d_out, int out_size, void* d_ws, size_t ws_size,
                              hipStream_t stream)
{
    const float* X = (const float*)d_in[0];
    float* out = (float*)d_out;

    char* ws = (char*)d_ws;
    float*         acc   = (float*)ws;                   // NACC fp32 slots
    float*         norms = (float*)(ws + 1024);          // 8192 fp32 (32 KB)
    unsigned char* Xq    = (unsigned char*)(ws + 1024 + 32768); // fp8 X, 4 MB

    norm_convert_kernel<<<NROWS / 4, 256, 0, stream>>>(X, Xq, norms, acc);
    pair_loss_gemm_kernel<<<NTRI, 256, 0, stream>>>(Xq, norms, acc);
    finalize_kernel<<<1, 64, 0, stream>>>(acc, out);
}